// Round 15
// baseline (1075.820 us; speedup 1.0000x reference)
//
#include <hip/hip_runtime.h>

typedef unsigned short u16;
typedef unsigned int   u32;
typedef __attribute__((ext_vector_type(8))) __bf16 bf16x8;
typedef __attribute__((ext_vector_type(4))) float  f32x4;

#define DEV __device__ __forceinline__

static constexpr int NN = 30000;
static constexpr int NE = 480000;
static constexpr int DD = 512;

static constexpr long OUT_FUSED = 0;
static constexpr long OUT_H     = 9000000;
static constexpr long OUT_IMG   = 24360000;
static constexpr long OUT_ATTR  = 33360000;
static constexpr long OUT_REL   = 42360000;

DEV float bf2f(u32 u){ u32 v = u << 16; float f; __builtin_memcpy(&f, &v, 4); return f; }
DEV u16 f2bf(float f){ u32 u; __builtin_memcpy(&u, &f, 4); u = (u + 0x7fffu + ((u >> 16) & 1u)) >> 16; return (u16)u; }
DEV u32 pk2(float a, float b){ return (u32)f2bf(a) | ((u32)f2bf(b) << 16); }

DEV void gll16(const void* g, void* l){
  __builtin_amdgcn_global_load_lds((const __attribute__((address_space(1))) void*)g,
                                   (__attribute__((address_space(3))) void*)l, 16, 0, 0);
}

// ---------------- merged prep: hist + x->bf16 + 10 weight pads ----------------
struct PadJob { const float* src; u16* dst; int rows, K, shift, total; };
struct PadJobs { PadJob j[10]; };
static constexpr int PREP_HIST = 1875;             // NE/256
static constexpr int PREP_CVT  = 7500;             // NN*DD/8/256
static constexpr int PREP_PADB = 384;              // blocks per pad job
__global__ void k_prep(const int* __restrict__ dst_idx, int* __restrict__ deg,
                       const float* __restrict__ x, u16* __restrict__ x_bf, PadJobs js){
  const int b = blockIdx.x;
  if (b < PREP_HIST){
    int e = b * 256 + threadIdx.x;
    if (e < NE) atomicAdd(&deg[dst_idx[e]], 1);
  } else if (b < PREP_HIST + PREP_CVT){
    int i = (b - PREP_HIST) * 256 + threadIdx.x;   // < 1,920,000
    const float4* s4 = (const float4*)x;
    float4 p = s4[2*i], q = s4[2*i+1];
    uint4 o; o.x = pk2(p.x,p.y); o.y = pk2(p.z,p.w); o.z = pk2(q.x,q.y); o.w = pk2(q.z,q.w);
    ((uint4*)x_bf)[i] = o;
  } else {
    const int pb = b - (PREP_HIST + PREP_CVT);
    const int job = pb / PREP_PADB, xb = pb - job * PREP_PADB;
    const PadJob jb = js.j[job];
    const int km = (1 << jb.shift) - 1;
    for (int i = xb * 256 + threadIdx.x; i < jb.total; i += PREP_PADB * 256){
      int r = i >> jb.shift, k = i & km;
      float v = (r < jb.rows && k < jb.K) ? jb.src[(size_t)r * jb.K + k] : 0.f;
      jb.dst[i] = f2bf(v);
    }
  }
}

__global__ void k_scan(const int* __restrict__ deg, int* __restrict__ rp, float* __restrict__ invd){
  __shared__ int sh[1024];
  const int t = threadIdx.x;
  const int base = t * 30;
  int sum = 0;
  #pragma unroll
  for (int i = 0; i < 30; ++i){
    int idx = base + i;
    sum += (idx < NN) ? deg[idx] : 0;
  }
  sh[t] = sum;
  __syncthreads();
  for (int off = 1; off < 1024; off <<= 1){
    int vv = (t >= off) ? sh[t - off] : 0;
    __syncthreads();
    sh[t] += vv;
    __syncthreads();
  }
  int run = (t == 0) ? 0 : sh[t - 1];
  #pragma unroll
  for (int i = 0; i < 30; ++i){
    int idx = base + i;
    if (idx < NN){
      int v = deg[idx];
      rp[idx]   = run;
      invd[idx] = 1.0f / (float)(v > 1 ? v : 1);
      run += v;
    }
  }
  if (t == 1023) rp[NN] = run;
}

__global__ void k_scatter(const int* __restrict__ src, const int* __restrict__ dst,
                          const int* __restrict__ rp, int* __restrict__ cur, int* __restrict__ col){
  int e = blockIdx.x * 256 + threadIdx.x;
  if (e >= NE) return;
  int d = dst[e];
  int p = atomicAdd(&cur[d], 1);
  col[rp[d] + p] = src[e];
}

// ---------------- mean aggregation (one wave per node, 8-deep MLP) ----------------
__global__ __launch_bounds__(256) void k_agg(const u16* __restrict__ Xb, const int* __restrict__ rp,
        const int* __restrict__ cols, const float* __restrict__ invd, u16* __restrict__ aggb)
{
  const int node = blockIdx.x * 4 + (threadIdx.x >> 6);
  const int l = threadIdx.x & 63;
  const int beg = rp[node], end = rp[node + 1];
  float a0=0,a1=0,a2=0,a3=0,a4=0,a5=0,a6=0,a7=0;
  const uint4* X4 = (const uint4*)Xb;
  auto accum = [&](uint4 v){
    a0 += bf2f(v.x & 0xffffu); a1 += bf2f(v.x >> 16);
    a2 += bf2f(v.y & 0xffffu); a3 += bf2f(v.y >> 16);
    a4 += bf2f(v.z & 0xffffu); a5 += bf2f(v.z >> 16);
    a6 += bf2f(v.w & 0xffffu); a7 += bf2f(v.w >> 16);
  };
  int e = beg;
  for (; e + 8 <= end; e += 8){
    const int s0 = cols[e],   s1 = cols[e+1], s2 = cols[e+2], s3 = cols[e+3];
    const int s4 = cols[e+4], s5 = cols[e+5], s6 = cols[e+6], s7 = cols[e+7];
    uint4 v0 = X4[(size_t)s0 * 64 + l];
    uint4 v1 = X4[(size_t)s1 * 64 + l];
    uint4 v2 = X4[(size_t)s2 * 64 + l];
    uint4 v3 = X4[(size_t)s3 * 64 + l];
    uint4 v4 = X4[(size_t)s4 * 64 + l];
    uint4 v5 = X4[(size_t)s5 * 64 + l];
    uint4 v6 = X4[(size_t)s6 * 64 + l];
    uint4 v7 = X4[(size_t)s7 * 64 + l];
    accum(v0); accum(v1); accum(v2); accum(v3);
    accum(v4); accum(v5); accum(v6); accum(v7);
  }
  for (; e + 4 <= end; e += 4){
    const int s0 = cols[e], s1 = cols[e+1], s2 = cols[e+2], s3 = cols[e+3];
    uint4 v0 = X4[(size_t)s0 * 64 + l];
    uint4 v1 = X4[(size_t)s1 * 64 + l];
    uint4 v2 = X4[(size_t)s2 * 64 + l];
    uint4 v3 = X4[(size_t)s3 * 64 + l];
    accum(v0); accum(v1); accum(v2); accum(v3);
  }
  for (; e < end; ++e){
    const int s = cols[e];
    accum(X4[(size_t)s * 64 + l]);
  }
  const float sc = invd[node];
  uint4 o;
  o.x = pk2(a0*sc, a1*sc); o.y = pk2(a2*sc, a3*sc);
  o.z = pk2(a4*sc, a5*sc); o.w = pk2(a6*sc, a7*sc);
  ((uint4*)aggb)[(size_t)node * 64 + l] = o;
}

// ---------------- shared bodies ----------------
struct SageA { const u16 *A1, *W1, *A2, *W2; const float* bias; u16* outB; float* outF; int relu; };
struct FuseJob { const void* A; const u16* W; const float* bias; float* outC; int K, Kp, akind; };
struct FuseJobs3 { FuseJob j[3]; };

// m97-structure sage body; lA/lB each 2*4096 u16
DEV void sage_body(const int c, const SageA sa, u16* lA, u16* lB){
  const int tid = threadIdx.x;
  const int w = tid >> 6, l = tid & 63;
  const int brow = (c >> 2) * 128, bcol = (c & 3) * 128;

  f32x4 acc[4][4];
  #pragma unroll
  for (int i = 0; i < 4; ++i)
    #pragma unroll
    for (int j = 0; j < 4; ++j) acc[i][j] = {0.f, 0.f, 0.f, 0.f};

  const int srow  = tid >> 2;
  const int kpart = (tid & 3) * 8;
  int g0 = brow + srow;      if (g0 >= NN) g0 = NN - 1;
  int g1 = brow + 64 + srow; if (g1 >= NN) g1 = NN - 1;

  auto stage = [&](int buf, int kt){
    const u16 *A, *W; int kk;
    if (kt < 16){ A = sa.A1; W = sa.W1; kk = kt * 32; } else { A = sa.A2; W = sa.W2; kk = (kt - 16) * 32; }
    gll16(A + (size_t)g0 * DD + kk + kpart, lA + buf * 4096 + (w * 16) * 32);
    gll16(A + (size_t)g1 * DD + kk + kpart, lA + buf * 4096 + (64 + w * 16) * 32);
    gll16(W + (size_t)(bcol + srow) * DD + kk + kpart,      lB + buf * 4096 + (w * 16) * 32);
    gll16(W + (size_t)(bcol + 64 + srow) * DD + kk + kpart, lB + buf * 4096 + (64 + w * 16) * 32);
  };

  stage(0, 0);
  __syncthreads();
  int cur = 0;
  for (int kt = 0; kt < 32; ++kt){
    if (kt + 1 < 32) stage(cur ^ 1, kt + 1);
    const u16* As = lA + cur * 4096 + ((w & 1) * 64 + (l & 15)) * 32 + (l >> 4) * 8;
    const u16* Bs = lB + cur * 4096 + ((w >> 1) * 64 + (l & 15)) * 32 + (l >> 4) * 8;
    bf16x8 a[4], b[4];
    #pragma unroll
    for (int i = 0; i < 4; ++i) a[i] = *(const bf16x8*)(As + i * 512);
    #pragma unroll
    for (int j = 0; j < 4; ++j) b[j] = *(const bf16x8*)(Bs + j * 512);
    #pragma unroll
    for (int i = 0; i < 4; ++i)
      #pragma unroll
      for (int j = 0; j < 4; ++j)
        acc[i][j] = __builtin_amdgcn_mfma_f32_16x16x32_bf16(a[i], b[j], acc[i][j], 0, 0, 0);
    __syncthreads();
    cur ^= 1;
  }

  const int wm = (w & 1) * 64, wn = (w >> 1) * 64;
  #pragma unroll
  for (int j = 0; j < 4; ++j){
    const int col = bcol + wn + j * 16 + (l & 15);
    const float bv = sa.bias[col];
    #pragma unroll
    for (int i = 0; i < 4; ++i){
      const int row0 = brow + wm + i * 16 + ((l >> 4) << 2);
      #pragma unroll
      for (int r2 = 0; r2 < 4; ++r2){
        const int row = row0 + r2;
        if (row < NN){
          float v = acc[i][j][r2] + bv;
          if (sa.relu) v = fmaxf(v, 0.f);
          sa.outB[(size_t)row * DD + col] = f2bf(v);
          if (sa.outF) sa.outF[(size_t)row * DD + col] = v;
        }
      }
    }
  }
}

// Fuse GEMM core: A reg-staged -> lA (2*2048 u16, 8KB LDS, shared by 4 waves);
// B per-wave REGISTER double-buffer (bA/bB named sets) loaded direct from global
// (no cross-wave B reuse -> LDS buys nothing; W is L2-hot). 2x-unrolled K loop.
DEV void fuse_gemm_acc(const void* __restrict__ Asrc, const u16* __restrict__ Wp,
                       const int K, const int Kp, const int akind,
                       const int brow, u16* lA, f32x4 (&acc)[4][5]){
  const int tid = threadIdx.x;
  const int w = tid >> 6, l = tid & 63;
  const int NT = Kp >> 5;          // 16 / 64 / 32 — always even
  const int colg = l & 15;
  const int grp  = l >> 4;

  const int arow = tid >> 2;
  const int agr  = tid & 3;
  int garow = brow + arow; if (garow >= NN) garow = NN - 1;

  // per-wave B row bases (rows < 384 padded)
  const u16* browp[5];
  #pragma unroll
  for (int j = 0; j < 5; ++j)
    browp[j] = Wp + (size_t)(w * 80 + j * 16 + colg) * Kp + grp * 8;

  bf16x8 bA[5], bB[5];
  auto loadB = [&](bf16x8 (&dst)[5], int kt){
    const int kk = kt * 32;
    #pragma unroll
    for (int j = 0; j < 5; ++j)
      dst[j] = *(const bf16x8*)(browp[j] + kk);
  };

  float4 pa, qa; uint4 ab;
  auto loadA = [&](int kt){
    if (akind == 0){
      const float* A = (const float*)Asrc;
      const int k0 = kt * 32 + agr * 8;
      const float* paddr = A + (size_t)garow * K + k0;
      if (k0 + 8 <= K){
        pa = *(const float4*)paddr;
        qa = *(const float4*)(paddr + 4);
      } else {
        float e[8];
        #pragma unroll
        for (int t = 0; t < 8; ++t){ int k = k0 + t; e[t] = (k < K) ? paddr[t] : 0.f; }
        pa.x=e[0]; pa.y=e[1]; pa.z=e[2]; pa.w=e[3];
        qa.x=e[4]; qa.y=e[5]; qa.z=e[6]; qa.w=e[7];
      }
    } else {
      ab = *(const uint4*)((const u16*)Asrc + (size_t)garow * Kp + kt * 32 + agr * 8);
    }
  };
  auto writeA = [&](int buf){
    uint4 t;
    if (akind == 0){
      t.x = pk2(pa.x, pa.y); t.y = pk2(pa.z, pa.w);
      t.z = pk2(qa.x, qa.y); t.w = pk2(qa.z, qa.w);
    } else t = ab;
    *(uint4*)(lA + buf * 2048 + arow * 32 + agr * 8) = t;
  };
  auto mfma5 = [&](int buf, bf16x8 (&b)[5]){
    const u16* As = lA + buf * 2048 + (l & 15) * 32 + grp * 8;
    bf16x8 a[4];
    #pragma unroll
    for (int i = 0; i < 4; ++i) a[i] = *(const bf16x8*)(As + i * 512);
    #pragma unroll
    for (int i = 0; i < 4; ++i)
      #pragma unroll
      for (int j = 0; j < 5; ++j)
        acc[i][j] = __builtin_amdgcn_mfma_f32_16x16x32_bf16(a[i], b[j], acc[i][j], 0, 0, 0);
  };

  loadA(0); writeA(0);
  loadB(bA, 0);
  __syncthreads();

  for (int kt = 0; kt < NT; kt += 2){
    // even step: compute with bA, prefetch kt+1 into bB
    if (kt + 1 < NT){ loadA(kt + 1); loadB(bB, kt + 1); }
    mfma5(0, bA);
    if (kt + 1 < NT) writeA(1);
    __syncthreads();
    // odd step: compute with bB, prefetch kt+2 into bA
    if (kt + 2 < NT){ loadA(kt + 2); loadB(bA, kt + 2); }
    if (kt + 1 < NT) mfma5(1, bB);
    if (kt + 2 < NT) writeA(0);
    __syncthreads();
  }
}

DEV void fuse_store(const FuseJob& jb, const int brow, f32x4 (&acc)[4][5]){
  const int tid = threadIdx.x;
  const int w = tid >> 6, l = tid & 63;
  float* __restrict__ outC = jb.outC;
  const float* __restrict__ bias = jb.bias;
  #pragma unroll
  for (int j = 0; j < 5; ++j){
    const int col = w * 80 + j * 16 + (l & 15);
    if (col < 300){
      const float bv = bias[col];
      #pragma unroll
      for (int i = 0; i < 4; ++i){
        const int row0 = brow + i * 16 + ((l >> 4) << 2);
        #pragma unroll
        for (int r = 0; r < 4; ++r){
          const int row = row0 + r;
          if (row < NN) outC[(size_t)row * 300 + col] = acc[i][j][r] + bv;
        }
      }
    }
  }
}

// ---------------- merged launch: sage L1 (940) + img/attr/rel fuse (1407) ----------------
__global__ __launch_bounds__(256) void k_sage_fuse(SageA sa, FuseJobs3 js){
  __shared__ u16 sm[16384];   // union: sage 32KB / fuse lA 8KB -> 32KB total
  const int bid = blockIdx.x;
  const int g = bid / 5, r5 = bid - g * 5;
  if (r5 < 2){
    const int c = g * 2 + r5;          // [0,940)
    sage_body(c, sa, sm, sm + 8192);
  } else {
    const int f = g * 3 + (r5 - 2);    // [0,1410)
    if (f < 1407){
      const int job = f / 469;
      const FuseJob jb = js.j[job];
      const int brow = (f - job * 469) * 64;
      f32x4 acc[4][5];
      #pragma unroll
      for (int i = 0; i < 4; ++i)
        #pragma unroll
        for (int j = 0; j < 5; ++j) acc[i][j] = {0.f, 0.f, 0.f, 0.f};
      fuse_gemm_acc(jb.A, jb.W, jb.K, jb.Kp, jb.akind, brow, sm, acc);
      fuse_store(jb, brow, acc);
    }
  }
}

// standalone sage (L2/L3), XCD-chunked grid 940
__global__ __launch_bounds__(256) void k_sage_gemm(SageA sa){
  __shared__ u16 sm[16384];
  const int bid = blockIdx.x;
  const int q = 117, r = 4;
  const int xcd = bid & 7, idx = bid >> 3;
  const int c = (xcd < r ? xcd * (q + 1) : r * (q + 1) + (xcd - r) * q) + idx;
  sage_body(c, sa, sm, sm + 8192);
}

// standalone single fuse job (gph), grid 469
__global__ __launch_bounds__(256) void k_fuse_one(FuseJob jb){
  __shared__ u16 sm[4096];
  const int brow = blockIdx.x * 64;
  f32x4 acc[4][5];
  #pragma unroll
  for (int i = 0; i < 4; ++i)
    #pragma unroll
    for (int j = 0; j < 5; ++j) acc[i][j] = {0.f, 0.f, 0.f, 0.f};
  fuse_gemm_acc(jb.A, jb.W, jb.K, jb.Kp, jb.akind, brow, sm, acc);
  fuse_store(jb, brow, acc);
}

// ---------------- gates + softmax + weighted sum + L2 norm (one wave per node) ----------------
__global__ __launch_bounds__(256) void k_fuse_final(
    const float* __restrict__ gph, const float* __restrict__ img,
    const float* __restrict__ attr, const float* __restrict__ rel,
    const float* __restrict__ Wfp, const float* __restrict__ bfp,
    float* __restrict__ fused)
{
  const int node = blockIdx.x * 4 + (threadIdx.x >> 6);
  const int l = threadIdx.x & 63;
  const size_t base = (size_t)node * 300;

  float e0[5], e1[5], e2[5], e3[5];
  float p0 = 0, p1 = 0, p2 = 0, p3 = 0;
  #pragma unroll
  for (int s = 0; s < 5; ++s){
    const int c = l + s * 64;
    const bool ok = (c < 300);
    const float wf = ok ? Wfp[c] : 0.f;
    const float a = ok ? gph[base + c]  : 0.f;
    const float b = ok ? img[base + c]  : 0.f;
    const float cc= ok ? attr[base + c] : 0.f;
    const float d = ok ? rel[base + c]  : 0.f;
    e0[s] = a; e1[s] = b; e2[s] = cc; e3[s] = d;
    p0 += wf * a; p1 += wf * b; p2 += wf * cc; p3 += wf * d;
  }
  #pragma unroll
  for (int off = 32; off >= 1; off >>= 1){
    p0 += __shfl_xor(p0, off); p1 += __shfl_xor(p1, off);
    p2 += __shfl_xor(p2, off); p3 += __shfl_xor(p3, off);
  }
  const float bb = bfp[0];
  const float g0 = p0 + bb, g1 = p1 + bb, g2 = p2 + bb, g3 = p3 + bb;
  const float m = fmaxf(fmaxf(g0, g1), fmaxf(g2, g3));
  float w0 = expf(g0 - m), w1 = expf(g1 - m), w2 = expf(g2 - m), w3 = expf(g3 - m);
  const float inv = 1.f / (w0 + w1 + w2 + w3);
  w0 *= inv; w1 *= inv; w2 *= inv; w3 *= inv;

  float f[5]; float nsq = 0;
  #pragma unroll
  for (int s = 0; s < 5; ++s){
    f[s] = w0 * e0[s] + w1 * e1[s] + w2 * e2[s] + w3 * e3[s];
    nsq += f[s] * f[s];
  }
  #pragma unroll
  for (int off = 32; off >= 1; off >>= 1) nsq += __shfl_xor(nsq, off);
  float nrm = sqrtf(nsq); nrm = fmaxf(nrm, 1e-12f);
  const float innv = 1.f / nrm;
  #pragma unroll
  for (int s = 0; s < 5; ++s){
    const int c = l + s * 64;
    if (c < 300) fused[base + c] = f[s] * innv;
  }
}

// ---------------- launch ----------------
extern "C" void kernel_launch(void* const* d_in, const int* in_sizes, int n_in,
                              void* d_out, int out_size, void* d_ws, size_t ws_size,
                              hipStream_t stream) {
  const float* x        = (const float*)d_in[0];
  const int*   ei       = (const int*)  d_in[1];
  const float* img_emb  = (const float*)d_in[2];
  const float* attr_emb = (const float*)d_in[3];
  const float* rel_emb  = (const float*)d_in[4];
  const float* Wl1 = (const float*)d_in[5],  *Wr1 = (const float*)d_in[6],  *b1 = (const float*)d_in[7];
  const float* Wl2 = (const float*)d_in[8],  *Wr2 = (const float*)d_in[9],  *b2 = (const float*)d_in[10];
  const float* Wl3 = (const float*)d_in[11], *Wr3 = (const float*)d_in[12], *b3 = (const float*)d_in[13];
  const float* Wg  = (const float*)d_in[14], *bg  = (const float*)d_in[15];
  const float* Wi  = (const float*)d_in[16], *bi  = (const float*)d_in[17];
  const float* Wa  = (const float*)d_in[18], *ba  = (const float*)d_in[19];
  const float* Wrl = (const float*)d_in[20], *brl = (const float*)d_in[21];
  const float* Wfp = (const float*)d_in[22], *bfp = (const float*)d_in[23];
  float* out = (float*)d_out;

  char* p = (char*)d_ws;
  auto carve = [&](size_t bytes) -> void* {
    void* r = (void*)p;
    p += (bytes + 255) & ~(size_t)255;
    return r;
  };
  int*   deg     = (int*)  carve(NN * 4);
  int*   cursor  = (int*)  carve(NN * 4);
  int*   row_ptr = (int*)  carve((NN + 1) * 4);
  float* inv_deg = (float*)carve(NN * 4);
  int*   csr_col = (int*)  carve(NE * 4);
  u16*   x_bf    = (u16*)  carve((size_t)NN * DD * 2);   // also reused for h3
  u16*   hA      = (u16*)  carve((size_t)NN * DD * 2);
  u16*   hB      = (u16*)  carve((size_t)NN * DD * 2);
  u16*   aggb    = (u16*)  carve((size_t)NN * DD * 2);
  float* gph     = (float*)carve((size_t)NN * 300 * 4);
  u16*   Wl1b = (u16*)carve(512 * 512 * 2);
  u16*   Wr1b = (u16*)carve(512 * 512 * 2);
  u16*   Wl2b = (u16*)carve(512 * 512 * 2);
  u16*   Wr2b = (u16*)carve(512 * 512 * 2);
  u16*   Wl3b = (u16*)carve(512 * 512 * 2);
  u16*   Wr3b = (u16*)carve(512 * 512 * 2);
  u16*   Wgb  = (u16*)carve(384 * 512 * 2);
  u16*   Wib  = (u16*)carve(384 * 2048 * 2);
  u16*   Wab  = (u16*)carve(384 * 1024 * 2);
  u16*   Wrlb = (u16*)carve(384 * 1024 * 2);

  hipMemsetAsync(deg, 0, NN * 4, stream);
  hipMemsetAsync(cursor, 0, NN * 4, stream);

  PadJobs js;
  js.j[0] = { Wl1, Wl1b, 512, 512,  9,  512*512 };
  js.j[1] = { Wr1, Wr1b, 512, 512,  9,  512*512 };
  js.j[2] = { Wl2, Wl2b, 512, 512,  9,  512*512 };
  js.j[3] = { Wr2, Wr2b, 512, 512,  9,  512*512 };
  js.j[4] = { Wl3, Wl3b, 512, 512,  9,  512*512 };
  js.j[5] = { Wr3, Wr3b, 512, 512,  9,  512*512 };
  js.j[6] = { Wg,  Wgb,  300, 512,  9,  384*512 };
  js.j[7] = { Wi,  Wib,  300, 2048, 11, 384*2048 };
  js.j[8] = { Wa,  Wab,  300, 1000, 10, 384*1024 };
  js.j[9] = { Wrl, Wrlb, 300, 1000, 10, 384*1024 };

  // merged prep: hist + x->bf16 + all weight pads (independent work, one launch)
  k_prep<<<PREP_HIST + PREP_CVT + 10 * PREP_PADB, 256, 0, stream>>>(ei + NE, deg, x, x_bf, js);
  k_scan<<<1, 1024, 0, stream>>>(deg, row_ptr, inv_deg);
  k_scatter<<<(NE + 255) / 256, 256, 0, stream>>>(ei, ei + NE, row_ptr, cursor, csr_col);

  // layer 1 aggregation
  k_agg<<<7500, 256, 0, stream>>>(x_bf, row_ptr, csr_col, inv_deg, aggb);

  // MERGED: sage layer 1 + img/attr/rel fusion projections (independent work)
  SageA s1 = { aggb, Wl1b, x_bf, Wr1b, b1, hA, nullptr, 1 };
  FuseJobs3 fj3;
  fj3.j[0] = { (const void*)img_emb,  Wib,  bi,  out + OUT_IMG,  2048, 2048, 0 };
  fj3.j[1] = { (const void*)attr_emb, Wab,  ba,  out + OUT_ATTR, 1000, 1024, 0 };
  fj3.j[2] = { (const void*)rel_emb,  Wrlb, brl, out + OUT_REL,  1000, 1024, 0 };
  k_sage_fuse<<<2350, 256, 0, stream>>>(s1, fj3);

  // layer 2
  k_agg<<<7500, 256, 0, stream>>>(hA, row_ptr, csr_col, inv_deg, aggb);
  SageA s2 = { aggb, Wl2b, hA, Wr2b, b2, hB, nullptr, 1 };
  k_sage_gemm<<<940, 256, 0, stream>>>(s2);
  // layer 3
  k_agg<<<7500, 256, 0, stream>>>(hB, row_ptr, csr_col, inv_deg, aggb);
  SageA s3 = { aggb, Wl3b, hB, Wr3b, b3, x_bf, out + OUT_H, 0 };
  k_sage_gemm<<<940, 256, 0, stream>>>(s3);

  // gph projection (depends on h3)
  FuseJob gj = { (const void*)x_bf, Wgb, bg, gph, 512, 512, 1 };
  k_fuse_one<<<469, 256, 0, stream>>>(gj);

  // gated fusion + normalize
  k_fuse_final<<<7500, 256, 0, stream>>>(gph, out + OUT_IMG, out + OUT_ATTR, out + OUT_REL,
                                         Wfp, bfp, out + OUT_FUSED);
}

// Round 16
// 842.319 us; speedup vs baseline: 1.2772x; 1.2772x over previous
//
#include <hip/hip_runtime.h>

typedef unsigned short u16;
typedef unsigned int   u32;
typedef __attribute__((ext_vector_type(8))) __bf16 bf16x8;
typedef __attribute__((ext_vector_type(4))) float  f32x4;

#define DEV __device__ __forceinline__

static constexpr int NN = 30000;
static constexpr int NE = 480000;
static constexpr int DD = 512;

static constexpr long OUT_FUSED = 0;
static constexpr long OUT_H     = 9000000;
static constexpr long OUT_IMG   = 24360000;
static constexpr long OUT_ATTR  = 33360000;
static constexpr long OUT_REL   = 42360000;

DEV float bf2f(u32 u){ u32 v = u << 16; float f; __builtin_memcpy(&f, &v, 4); return f; }
DEV u16 f2bf(float f){ u32 u; __builtin_memcpy(&u, &f, 4); u = (u + 0x7fffu + ((u >> 16) & 1u)) >> 16; return (u16)u; }
DEV u32 pk2(float a, float b){ return (u32)f2bf(a) | ((u32)f2bf(b) << 16); }

DEV void gll16(const void* g, void* l){
  __builtin_amdgcn_global_load_lds((const __attribute__((address_space(1))) void*)g,
                                   (__attribute__((address_space(3))) void*)l, 16, 0, 0);
}

// ---------------- merged prep: hist + x->bf16 + 10 weight pads ----------------
struct PadJob { const float* src; u16* dst; int rows, K, shift, total; };
struct PadJobs { PadJob j[10]; };
static constexpr int PREP_HIST = 1875;             // NE/256
static constexpr int PREP_CVT  = 7500;             // NN*DD/8/256
static constexpr int PREP_PADB = 384;              // blocks per pad job
__global__ void k_prep(const int* __restrict__ dst_idx, int* __restrict__ deg,
                       const float* __restrict__ x, u16* __restrict__ x_bf, PadJobs js){
  const int b = blockIdx.x;
  if (b < PREP_HIST){
    int e = b * 256 + threadIdx.x;
    if (e < NE) atomicAdd(&deg[dst_idx[e]], 1);
  } else if (b < PREP_HIST + PREP_CVT){
    int i = (b - PREP_HIST) * 256 + threadIdx.x;   // < 1,920,000
    const float4* s4 = (const float4*)x;
    float4 p = s4[2*i], q = s4[2*i+1];
    uint4 o; o.x = pk2(p.x,p.y); o.y = pk2(p.z,p.w); o.z = pk2(q.x,q.y); o.w = pk2(q.z,q.w);
    ((uint4*)x_bf)[i] = o;
  } else {
    const int pb = b - (PREP_HIST + PREP_CVT);
    const int job = pb / PREP_PADB, xb = pb - job * PREP_PADB;
    const PadJob jb = js.j[job];
    const int km = (1 << jb.shift) - 1;
    for (int i = xb * 256 + threadIdx.x; i < jb.total; i += PREP_PADB * 256){
      int r = i >> jb.shift, k = i & km;
      float v = (r < jb.rows && k < jb.K) ? jb.src[(size_t)r * jb.K + k] : 0.f;
      jb.dst[i] = f2bf(v);
    }
  }
}

__global__ void k_scan(const int* __restrict__ deg, int* __restrict__ rp, float* __restrict__ invd){
  __shared__ int sh[1024];
  const int t = threadIdx.x;
  const int base = t * 30;
  int sum = 0;
  #pragma unroll
  for (int i = 0; i < 30; ++i){
    int idx = base + i;
    sum += (idx < NN) ? deg[idx] : 0;
  }
  sh[t] = sum;
  __syncthreads();
  for (int off = 1; off < 1024; off <<= 1){
    int vv = (t >= off) ? sh[t - off] : 0;
    __syncthreads();
    sh[t] += vv;
    __syncthreads();
  }
  int run = (t == 0) ? 0 : sh[t - 1];
  #pragma unroll
  for (int i = 0; i < 30; ++i){
    int idx = base + i;
    if (idx < NN){
      int v = deg[idx];
      rp[idx]   = run;
      invd[idx] = 1.0f / (float)(v > 1 ? v : 1);
      run += v;
    }
  }
  if (t == 1023) rp[NN] = run;
}

__global__ void k_scatter(const int* __restrict__ src, const int* __restrict__ dst,
                          const int* __restrict__ rp, int* __restrict__ cur, int* __restrict__ col){
  int e = blockIdx.x * 256 + threadIdx.x;
  if (e >= NE) return;
  int d = dst[e];
  int p = atomicAdd(&cur[d], 1);
  col[rp[d] + p] = src[e];
}

// ---------------- mean aggregation (one wave per node, 8-deep MLP) ----------------
__global__ __launch_bounds__(256) void k_agg(const u16* __restrict__ Xb, const int* __restrict__ rp,
        const int* __restrict__ cols, const float* __restrict__ invd, u16* __restrict__ aggb)
{
  const int node = blockIdx.x * 4 + (threadIdx.x >> 6);
  const int l = threadIdx.x & 63;
  const int beg = rp[node], end = rp[node + 1];
  float a0=0,a1=0,a2=0,a3=0,a4=0,a5=0,a6=0,a7=0;
  const uint4* X4 = (const uint4*)Xb;
  auto accum = [&](uint4 v){
    a0 += bf2f(v.x & 0xffffu); a1 += bf2f(v.x >> 16);
    a2 += bf2f(v.y & 0xffffu); a3 += bf2f(v.y >> 16);
    a4 += bf2f(v.z & 0xffffu); a5 += bf2f(v.z >> 16);
    a6 += bf2f(v.w & 0xffffu); a7 += bf2f(v.w >> 16);
  };
  int e = beg;
  for (; e + 8 <= end; e += 8){
    const int s0 = cols[e],   s1 = cols[e+1], s2 = cols[e+2], s3 = cols[e+3];
    const int s4 = cols[e+4], s5 = cols[e+5], s6 = cols[e+6], s7 = cols[e+7];
    uint4 v0 = X4[(size_t)s0 * 64 + l];
    uint4 v1 = X4[(size_t)s1 * 64 + l];
    uint4 v2 = X4[(size_t)s2 * 64 + l];
    uint4 v3 = X4[(size_t)s3 * 64 + l];
    uint4 v4 = X4[(size_t)s4 * 64 + l];
    uint4 v5 = X4[(size_t)s5 * 64 + l];
    uint4 v6 = X4[(size_t)s6 * 64 + l];
    uint4 v7 = X4[(size_t)s7 * 64 + l];
    accum(v0); accum(v1); accum(v2); accum(v3);
    accum(v4); accum(v5); accum(v6); accum(v7);
  }
  for (; e + 4 <= end; e += 4){
    const int s0 = cols[e], s1 = cols[e+1], s2 = cols[e+2], s3 = cols[e+3];
    uint4 v0 = X4[(size_t)s0 * 64 + l];
    uint4 v1 = X4[(size_t)s1 * 64 + l];
    uint4 v2 = X4[(size_t)s2 * 64 + l];
    uint4 v3 = X4[(size_t)s3 * 64 + l];
    accum(v0); accum(v1); accum(v2); accum(v3);
  }
  for (; e < end; ++e){
    const int s = cols[e];
    accum(X4[(size_t)s * 64 + l]);
  }
  const float sc = invd[node];
  uint4 o;
  o.x = pk2(a0*sc, a1*sc); o.y = pk2(a2*sc, a3*sc);
  o.z = pk2(a4*sc, a5*sc); o.w = pk2(a6*sc, a7*sc);
  ((uint4*)aggb)[(size_t)node * 64 + l] = o;
}

// ---------------- shared bodies ----------------
struct SageA { const u16 *A1, *W1, *A2, *W2; const float* bias; u16* outB; float* outF; int relu; };
struct FuseJob { const void* A; const u16* W; const float* bias; float* outC; int K, Kp, akind; };
struct FuseJobs3 { FuseJob j[3]; };

// m97-structure sage body; lA/lB each 2*4096 u16
DEV void sage_body(const int c, const SageA sa, u16* lA, u16* lB){
  const int tid = threadIdx.x;
  const int w = tid >> 6, l = tid & 63;
  const int brow = (c >> 2) * 128, bcol = (c & 3) * 128;

  f32x4 acc[4][4];
  #pragma unroll
  for (int i = 0; i < 4; ++i)
    #pragma unroll
    for (int j = 0; j < 4; ++j) acc[i][j] = {0.f, 0.f, 0.f, 0.f};

  const int srow  = tid >> 2;
  const int kpart = (tid & 3) * 8;
  int g0 = brow + srow;      if (g0 >= NN) g0 = NN - 1;
  int g1 = brow + 64 + srow; if (g1 >= NN) g1 = NN - 1;

  auto stage = [&](int buf, int kt){
    const u16 *A, *W; int kk;
    if (kt < 16){ A = sa.A1; W = sa.W1; kk = kt * 32; } else { A = sa.A2; W = sa.W2; kk = (kt - 16) * 32; }
    gll16(A + (size_t)g0 * DD + kk + kpart, lA + buf * 4096 + (w * 16) * 32);
    gll16(A + (size_t)g1 * DD + kk + kpart, lA + buf * 4096 + (64 + w * 16) * 32);
    gll16(W + (size_t)(bcol + srow) * DD + kk + kpart,      lB + buf * 4096 + (w * 16) * 32);
    gll16(W + (size_t)(bcol + 64 + srow) * DD + kk + kpart, lB + buf * 4096 + (64 + w * 16) * 32);
  };

  stage(0, 0);
  __syncthreads();
  int cur = 0;
  for (int kt = 0; kt < 32; ++kt){
    if (kt + 1 < 32) stage(cur ^ 1, kt + 1);
    const u16* As = lA + cur * 4096 + ((w & 1) * 64 + (l & 15)) * 32 + (l >> 4) * 8;
    const u16* Bs = lB + cur * 4096 + ((w >> 1) * 64 + (l & 15)) * 32 + (l >> 4) * 8;
    bf16x8 a[4], b[4];
    #pragma unroll
    for (int i = 0; i < 4; ++i) a[i] = *(const bf16x8*)(As + i * 512);
    #pragma unroll
    for (int j = 0; j < 4; ++j) b[j] = *(const bf16x8*)(Bs + j * 512);
    #pragma unroll
    for (int i = 0; i < 4; ++i)
      #pragma unroll
      for (int j = 0; j < 4; ++j)
        acc[i][j] = __builtin_amdgcn_mfma_f32_16x16x32_bf16(a[i], b[j], acc[i][j], 0, 0, 0);
    __syncthreads();
    cur ^= 1;
  }

  const int wm = (w & 1) * 64, wn = (w >> 1) * 64;
  #pragma unroll
  for (int j = 0; j < 4; ++j){
    const int col = bcol + wn + j * 16 + (l & 15);
    const float bv = sa.bias[col];
    #pragma unroll
    for (int i = 0; i < 4; ++i){
      const int row0 = brow + wm + i * 16 + ((l >> 4) << 2);
      #pragma unroll
      for (int r2 = 0; r2 < 4; ++r2){
        const int row = row0 + r2;
        if (row < NN){
          float v = acc[i][j][r2] + bv;
          if (sa.relu) v = fmaxf(v, 0.f);
          sa.outB[(size_t)row * DD + col] = f2bf(v);
          if (sa.outF) sa.outF[(size_t)row * DD + col] = v;
        }
      }
    }
  }
}

// R6-proven fuse GEMM core (reg-staged A -> lA, gll B -> lB, 2-buffer, accumulate only).
// lA: 2*2048 u16 (8KB), lB: 2*10240 u16 (40KB).
DEV void fuse_gemm_acc(const void* __restrict__ Asrc, const u16* __restrict__ Wp,
                       const int K, const int Kp, const int akind,
                       const int brow, u16* lA, u16* lB, f32x4 (&acc)[4][5]){
  const int tid = threadIdx.x;
  const int w = tid >> 6, l = tid & 63;
  const int NT = Kp >> 5;

  const int arow = tid >> 2;
  const int agr  = tid & 3;
  int garow = brow + arow; if (garow >= NN) garow = NN - 1;

  auto stageB = [&](int buf, int kt){
    const int kk = kt * 32;
    #pragma unroll
    for (int is = 0; is < 5; ++is){
      const int s = tid + 256 * is;
      gll16(Wp + (size_t)(s >> 2) * Kp + kk + (s & 3) * 8,
            lB + buf * 10240 + (w * 64 + 256 * is) * 8);
    }
  };

  float4 pa, qa; uint4 ab;
  auto loadA = [&](int kt){
    if (akind == 0){
      const float* A = (const float*)Asrc;
      const int k0 = kt * 32 + agr * 8;
      const float* paddr = A + (size_t)garow * K + k0;
      if (k0 + 8 <= K){
        pa = *(const float4*)paddr;
        qa = *(const float4*)(paddr + 4);
      } else {
        float e[8];
        #pragma unroll
        for (int t = 0; t < 8; ++t){ int k = k0 + t; e[t] = (k < K) ? paddr[t] : 0.f; }
        pa.x=e[0]; pa.y=e[1]; pa.z=e[2]; pa.w=e[3];
        qa.x=e[4]; qa.y=e[5]; qa.z=e[6]; qa.w=e[7];
      }
    } else {
      ab = *(const uint4*)((const u16*)Asrc + (size_t)garow * Kp + kt * 32 + agr * 8);
    }
  };
  auto writeA = [&](int buf){
    uint4 t;
    if (akind == 0){
      t.x = pk2(pa.x, pa.y); t.y = pk2(pa.z, pa.w);
      t.z = pk2(qa.x, qa.y); t.w = pk2(qa.z, qa.w);
    } else t = ab;
    *(uint4*)(lA + buf * 2048 + arow * 32 + agr * 8) = t;
  };

  loadA(0); writeA(0);
  stageB(0, 0);
  __syncthreads();

  int cur = 0;
  for (int kt = 0; kt < NT; ++kt){
    const bool pf = (kt + 1 < NT);
    if (pf){
      loadA(kt + 1);
      stageB(cur ^ 1, kt + 1);
    }
    const u16* As = lA + cur * 2048 + (l & 15) * 32 + (l >> 4) * 8;
    const u16* Bs = lB + cur * 10240 + (w * 80 + (l & 15)) * 32 + (l >> 4) * 8;
    bf16x8 a[4], b[5];
    #pragma unroll
    for (int i = 0; i < 4; ++i) a[i] = *(const bf16x8*)(As + i * 512);
    #pragma unroll
    for (int j = 0; j < 5; ++j) b[j] = *(const bf16x8*)(Bs + j * 512);
    #pragma unroll
    for (int i = 0; i < 4; ++i)
      #pragma unroll
      for (int j = 0; j < 5; ++j)
        acc[i][j] = __builtin_amdgcn_mfma_f32_16x16x32_bf16(a[i], b[j], acc[i][j], 0, 0, 0);
    if (pf) writeA(cur ^ 1);
    __syncthreads();
    cur ^= 1;
  }
}

DEV void fuse_store(const FuseJob& jb, const int brow, f32x4 (&acc)[4][5]){
  const int tid = threadIdx.x;
  const int w = tid >> 6, l = tid & 63;
  float* __restrict__ outC = jb.outC;
  const float* __restrict__ bias = jb.bias;
  #pragma unroll
  for (int j = 0; j < 5; ++j){
    const int col = w * 80 + j * 16 + (l & 15);
    if (col < 300){
      const float bv = bias[col];
      #pragma unroll
      for (int i = 0; i < 4; ++i){
        const int row0 = brow + i * 16 + ((l >> 4) << 2);
        #pragma unroll
        for (int r = 0; r < 4; ++r){
          const int row = row0 + r;
          if (row < NN) outC[(size_t)row * 300 + col] = acc[i][j][r] + bv;
        }
      }
    }
  }
}

// ---------------- merged launch: sage L1 (940) + img/attr/rel fuse (1407) ----------------
__global__ __launch_bounds__(256) void k_sage_fuse(SageA sa, FuseJobs3 js){
  __shared__ u16 sm[24576];   // union: sage 32KB / fuse lA 8KB + lB 40KB = 48KB
  const int bid = blockIdx.x;
  const int g = bid / 5, r5 = bid - g * 5;
  if (r5 < 2){
    const int c = g * 2 + r5;          // [0,940)
    sage_body(c, sa, sm, sm + 8192);
  } else {
    const int f = g * 3 + (r5 - 2);    // [0,1410)
    if (f < 1407){
      const int job = f / 469;
      const FuseJob jb = js.j[job];
      const int brow = (f - job * 469) * 64;
      f32x4 acc[4][5];
      #pragma unroll
      for (int i = 0; i < 4; ++i)
        #pragma unroll
        for (int j = 0; j < 5; ++j) acc[i][j] = {0.f, 0.f, 0.f, 0.f};
      fuse_gemm_acc(jb.A, jb.W, jb.K, jb.Kp, jb.akind, brow, sm, sm + 4096, acc);
      fuse_store(jb, brow, acc);
    }
  }
}

// standalone sage (L2/L3), XCD-chunked grid 940
__global__ __launch_bounds__(256) void k_sage_gemm(SageA sa){
  __shared__ u16 sm[16384];
  const int bid = blockIdx.x;
  const int q = 117, r = 4;
  const int xcd = bid & 7, idx = bid >> 3;
  const int c = (xcd < r ? xcd * (q + 1) : r * (q + 1) + (xcd - r) * q) + idx;
  sage_body(c, sa, sm, sm + 8192);
}

// standalone single fuse job (gph), grid 469
__global__ __launch_bounds__(256) void k_fuse_one(FuseJob jb){
  __shared__ u16 sm[24576];
  const int brow = blockIdx.x * 64;
  f32x4 acc[4][5];
  #pragma unroll
  for (int i = 0; i < 4; ++i)
    #pragma unroll
    for (int j = 0; j < 5; ++j) acc[i][j] = {0.f, 0.f, 0.f, 0.f};
  fuse_gemm_acc(jb.A, jb.W, jb.K, jb.Kp, jb.akind, brow, sm, sm + 4096, acc);
  fuse_store(jb, brow, acc);
}

// ---------------- gates + softmax + weighted sum + L2 norm (one wave per node) ----------------
__global__ __launch_bounds__(256) void k_fuse_final(
    const float* __restrict__ gph, const float* __restrict__ img,
    const float* __restrict__ attr, const float* __restrict__ rel,
    const float* __restrict__ Wfp, const float* __restrict__ bfp,
    float* __restrict__ fused)
{
  const int node = blockIdx.x * 4 + (threadIdx.x >> 6);
  const int l = threadIdx.x & 63;
  const size_t base = (size_t)node * 300;

  float e0[5], e1[5], e2[5], e3[5];
  float p0 = 0, p1 = 0, p2 = 0, p3 = 0;
  #pragma unroll
  for (int s = 0; s < 5; ++s){
    const int c = l + s * 64;
    const bool ok = (c < 300);
    const float wf = ok ? Wfp[c] : 0.f;
    const float a = ok ? gph[base + c]  : 0.f;
    const float b = ok ? img[base + c]  : 0.f;
    const float cc= ok ? attr[base + c] : 0.f;
    const float d = ok ? rel[base + c]  : 0.f;
    e0[s] = a; e1[s] = b; e2[s] = cc; e3[s] = d;
    p0 += wf * a; p1 += wf * b; p2 += wf * cc; p3 += wf * d;
  }
  #pragma unroll
  for (int off = 32; off >= 1; off >>= 1){
    p0 += __shfl_xor(p0, off); p1 += __shfl_xor(p1, off);
    p2 += __shfl_xor(p2, off); p3 += __shfl_xor(p3, off);
  }
  const float bb = bfp[0];
  const float g0 = p0 + bb, g1 = p1 + bb, g2 = p2 + bb, g3 = p3 + bb;
  const float m = fmaxf(fmaxf(g0, g1), fmaxf(g2, g3));
  float w0 = expf(g0 - m), w1 = expf(g1 - m), w2 = expf(g2 - m), w3 = expf(g3 - m);
  const float inv = 1.f / (w0 + w1 + w2 + w3);
  w0 *= inv; w1 *= inv; w2 *= inv; w3 *= inv;

  float f[5]; float nsq = 0;
  #pragma unroll
  for (int s = 0; s < 5; ++s){
    f[s] = w0 * e0[s] + w1 * e1[s] + w2 * e2[s] + w3 * e3[s];
    nsq += f[s] * f[s];
  }
  #pragma unroll
  for (int off = 32; off >= 1; off >>= 1) nsq += __shfl_xor(nsq, off);
  float nrm = sqrtf(nsq); nrm = fmaxf(nrm, 1e-12f);
  const float innv = 1.f / nrm;
  #pragma unroll
  for (int s = 0; s < 5; ++s){
    const int c = l + s * 64;
    if (c < 300) fused[base + c] = f[s] * innv;
  }
}

// ---------------- launch ----------------
extern "C" void kernel_launch(void* const* d_in, const int* in_sizes, int n_in,
                              void* d_out, int out_size, void* d_ws, size_t ws_size,
                              hipStream_t stream) {
  const float* x        = (const float*)d_in[0];
  const int*   ei       = (const int*)  d_in[1];
  const float* img_emb  = (const float*)d_in[2];
  const float* attr_emb = (const float*)d_in[3];
  const float* rel_emb  = (const float*)d_in[4];
  const float* Wl1 = (const float*)d_in[5],  *Wr1 = (const float*)d_in[6],  *b1 = (const float*)d_in[7];
  const float* Wl2 = (const float*)d_in[8],  *Wr2 = (const float*)d_in[9],  *b2 = (const float*)d_in[10];
  const float* Wl3 = (const float*)d_in[11], *Wr3 = (const float*)d_in[12], *b3 = (const float*)d_in[13];
  const float* Wg  = (const float*)d_in[14], *bg  = (const float*)d_in[15];
  const float* Wi  = (const float*)d_in[16], *bi  = (const float*)d_in[17];
  const float* Wa  = (const float*)d_in[18], *ba  = (const float*)d_in[19];
  const float* Wrl = (const float*)d_in[20], *brl = (const float*)d_in[21];
  const float* Wfp = (const float*)d_in[22], *bfp = (const float*)d_in[23];
  float* out = (float*)d_out;

  char* p = (char*)d_ws;
  auto carve = [&](size_t bytes) -> void* {
    void* r = (void*)p;
    p += (bytes + 255) & ~(size_t)255;
    return r;
  };
  int*   deg     = (int*)  carve(NN * 4);
  int*   cursor  = (int*)  carve(NN * 4);
  int*   row_ptr = (int*)  carve((NN + 1) * 4);
  float* inv_deg = (float*)carve(NN * 4);
  int*   csr_col = (int*)  carve(NE * 4);
  u16*   x_bf    = (u16*)  carve((size_t)NN * DD * 2);   // also reused for h3
  u16*   hA      = (u16*)  carve((size_t)NN * DD * 2);
  u16*   hB      = (u16*)  carve((size_t)NN * DD * 2);
  u16*   aggb    = (u16*)  carve((size_t)NN * DD * 2);
  float* gph     = (float*)carve((size_t)NN * 300 * 4);
  u16*   Wl1b = (u16*)carve(512 * 512 * 2);
  u16*   Wr1b = (u16*)carve(512 * 512 * 2);
  u16*   Wl2b = (u16*)carve(512 * 512 * 2);
  u16*   Wr2b = (u16*)carve(512 * 512 * 2);
  u16*   Wl3b = (u16*)carve(512 * 512 * 2);
  u16*   Wr3b = (u16*)carve(512 * 512 * 2);
  u16*   Wgb  = (u16*)carve(384 * 512 * 2);
  u16*   Wib  = (u16*)carve(384 * 2048 * 2);
  u16*   Wab  = (u16*)carve(384 * 1024 * 2);
  u16*   Wrlb = (u16*)carve(384 * 1024 * 2);

  hipMemsetAsync(deg, 0, NN * 4, stream);
  hipMemsetAsync(cursor, 0, NN * 4, stream);

  PadJobs js;
  js.j[0] = { Wl1, Wl1b, 512, 512,  9,  512*512 };
  js.j[1] = { Wr1, Wr1b, 512, 512,  9,  512*512 };
  js.j[2] = { Wl2, Wl2b, 512, 512,  9,  512*512 };
  js.j[3] = { Wr2, Wr2b, 512, 512,  9,  512*512 };
  js.j[4] = { Wl3, Wl3b, 512, 512,  9,  512*512 };
  js.j[5] = { Wr3, Wr3b, 512, 512,  9,  512*512 };
  js.j[6] = { Wg,  Wgb,  300, 512,  9,  384*512 };
  js.j[7] = { Wi,  Wib,  300, 2048, 11, 384*2048 };
  js.j[8] = { Wa,  Wab,  300, 1000, 10, 384*1024 };
  js.j[9] = { Wrl, Wrlb, 300, 1000, 10, 384*1024 };

  // merged prep: hist + x->bf16 + all weight pads (independent work, one launch)
  k_prep<<<PREP_HIST + PREP_CVT + 10 * PREP_PADB, 256, 0, stream>>>(ei + NE, deg, x, x_bf, js);
  k_scan<<<1, 1024, 0, stream>>>(deg, row_ptr, inv_deg);
  k_scatter<<<(NE + 255) / 256, 256, 0, stream>>>(ei, ei + NE, row_ptr, cursor, csr_col);

  // layer 1 aggregation
  k_agg<<<7500, 256, 0, stream>>>(x_bf, row_ptr, csr_col, inv_deg, aggb);

  // MERGED: sage layer 1 + img/attr/rel fusion projections (independent work)
  SageA s1 = { aggb, Wl1b, x_bf, Wr1b, b1, hA, nullptr, 1 };
  FuseJobs3 fj3;
  fj3.j[0] = { (const void*)img_emb,  Wib,  bi,  out + OUT_IMG,  2048, 2048, 0 };
  fj3.j[1] = { (const void*)attr_emb, Wab,  ba,  out + OUT_ATTR, 1000, 1024, 0 };
  fj3.j[2] = { (const void*)rel_emb,  Wrlb, brl, out + OUT_REL,  1000, 1024, 0 };
  k_sage_fuse<<<2350, 256, 0, stream>>>(s1, fj3);

  // layer 2
  k_agg<<<7500, 256, 0, stream>>>(hA, row_ptr, csr_col, inv_deg, aggb);
  SageA s2 = { aggb, Wl2b, hA, Wr2b, b2, hB, nullptr, 1 };
  k_sage_gemm<<<940, 256, 0, stream>>>(s2);
  // layer 3
  k_agg<<<7500, 256, 0, stream>>>(hB, row_ptr, csr_col, inv_deg, aggb);
  SageA s3 = { aggb, Wl3b, hB, Wr3b, b3, x_bf, out + OUT_H, 0 };
  k_sage_gemm<<<940, 256, 0, stream>>>(s3);

  // gph projection (depends on h3)
  FuseJob gj = { (const void*)x_bf, Wgb, bg, gph, 512, 512, 1 };
  k_fuse_one<<<469, 256, 0, stream>>>(gj);

  // gated fusion + normalize
  k_fuse_final<<<7500, 256, 0, stream>>>(gph, out + OUT_IMG, out + OUT_ATTR, out + OUT_REL,
                                         Wfp, bfp, out + OUT_FUSED);
}